// Round 3
// baseline (126.168 us; speedup 1.0000x reference)
//
#include <hip/hip_runtime.h>
#include <math.h>

#define N_IMG 64
#define D_CH  128
#define P_PIX 4096
#define K_CL  32
#define S_SPL 8
#define P_BLK (P_PIX / S_SPL)   // 512 pixels per block
#define T_PX  64                // tile pixels
#define N_TILE (P_BLK / T_PX)   // 8 tiles per block
#define AT_LD 36                // padded leading dim for soft-assign tile

// Swizzled quad base (word index) for the x tile: row d (0..127), pixel-quad p4 (0..15).
// Keeps rows b128-contiguous while spreading cross-row column reads across banks.
__device__ __forceinline__ int xw_quad(int d, int p4) {
    return (d << 6) + ((p4 ^ ((d >> 2) & 15)) << 2);
}

__global__ __launch_bounds__(256)
void netvlad_main(const float* __restrict__ x, const float* __restrict__ w,
                  float* __restrict__ aggp, float* __restrict__ asump)
{
    __shared__ __align__(16) float wt[D_CH][K_CL];   // conv_w transposed [d][k]
    __shared__ __align__(16) float xl[D_CH * T_PX];  // swizzled x tile
    __shared__ __align__(16) float at[T_PX][AT_LD];  // logits -> scaled soft-assign
    __shared__ float sS[T_PX];                        // 1/max(norm,eps)
    __shared__ float nS[T_PX];                        // max(norm,eps)
    __shared__ float nrm4[4][T_PX];
    __shared__ float asw[8][K_CL];

    const int tid = threadIdx.x;
    const int n   = blockIdx.x >> 3;
    const int ps  = blockIdx.x & 7;

    // load conv_w transposed (once per block)
    for (int i = tid; i < K_CL * D_CH; i += 256) {
        wt[i & 127][i >> 7] = w[i];
    }

    float acc[4][4];
    #pragma unroll
    for (int i = 0; i < 4; ++i)
        #pragma unroll
        for (int j = 0; j < 4; ++j) acc[i][j] = 0.0f;
    float asum_acc = 0.0f;

    // per-phase thread roles
    const int l_dh = tid >> 7;            // logits: d-half 0/1
    const int l_kg = tid & 7;             // logits: k0 = 4*l_kg
    const int l_pg = (tid & 127) >> 3;    // logits: p0 = 4*l_pg
    const int s_p  = tid >> 2;            // softmax pixel
    const int s_q  = tid & 3;             // softmax octet
    const int a_kg = tid >> 5;            // agg: k0 = 4*a_kg
    const int a_dg = tid & 31;            // agg: d0 = 4*a_dg
    const int u_k  = tid & 31;            // asum: k
    const int u_ph = tid >> 5;            // asum: pixel octet

    const float* xin = x + (size_t)n * D_CH * P_PIX + ps * P_BLK;

    for (int t = 0; t < N_TILE; ++t) {
        // ---------- stage tile into LDS (swizzled), coalesced float4 ----------
        const float* xt = xin + t * T_PX;
        #pragma unroll
        for (int it = 0; it < 8; ++it) {
            int i  = (it << 8) + tid;     // 0..2047 quads
            int d  = i >> 4;
            int p4 = i & 15;
            float4 v = *(const float4*)(xt + d * P_PIX + (p4 << 2));
            *(float4*)(xl + xw_quad(d, p4)) = v;
        }
        __syncthreads();

        // ---------- per-pixel sum of squares ----------
        {
            int p = tid & 63, dq = tid >> 6;
            int p4 = p >> 2, pm = p & 3;
            float ss = 0.0f;
            #pragma unroll
            for (int j = 0; j < 32; ++j) {
                int d = (dq << 5) + j;
                float v = xl[xw_quad(d, p4) + pm];
                ss += v * v;
            }
            nrm4[dq][p] = ss;
        }
        __syncthreads();
        if (tid < T_PX) {
            float s2 = nrm4[0][tid] + nrm4[1][tid] + nrm4[2][tid] + nrm4[3][tid];
            float nn = fmaxf(sqrtf(s2), 1e-12f);
            nS[tid] = nn;
            sS[tid] = 1.0f / nn;
        }
        __syncthreads();

        // ---------- logits: at[p][k] = sum_d x[d,p]*w[k,d] (unscaled) ----------
        {
            float lg[4][4];
            #pragma unroll
            for (int i = 0; i < 4; ++i)
                #pragma unroll
                for (int j = 0; j < 4; ++j) lg[i][j] = 0.0f;
            const int p0 = l_pg << 2;
            const int k0 = l_kg << 2;
            const int dbase = l_dh << 6;
            #pragma unroll
            for (int dd = 0; dd < 64; ++dd) {
                int d = dbase + dd;
                float4 xv = *(const float4*)(xl + xw_quad(d, l_pg));
                float4 wv = *(const float4*)(&wt[d][k0]);
                lg[0][0] += xv.x * wv.x; lg[0][1] += xv.x * wv.y; lg[0][2] += xv.x * wv.z; lg[0][3] += xv.x * wv.w;
                lg[1][0] += xv.y * wv.x; lg[1][1] += xv.y * wv.y; lg[1][2] += xv.y * wv.z; lg[1][3] += xv.y * wv.w;
                lg[2][0] += xv.z * wv.x; lg[2][1] += xv.z * wv.y; lg[2][2] += xv.z * wv.z; lg[2][3] += xv.z * wv.w;
                lg[3][0] += xv.w * wv.x; lg[3][1] += xv.w * wv.y; lg[3][2] += xv.w * wv.z; lg[3][3] += xv.w * wv.w;
            }
            if (l_dh == 0) {
                #pragma unroll
                for (int pi = 0; pi < 4; ++pi) {
                    *(float4*)&at[p0 + pi][k0] =
                        make_float4(lg[pi][0], lg[pi][1], lg[pi][2], lg[pi][3]);
                }
            }
            __syncthreads();
            if (l_dh == 1) {
                #pragma unroll
                for (int pi = 0; pi < 4; ++pi) {
                    float4 o = *(float4*)&at[p0 + pi][k0];
                    o.x += lg[pi][0]; o.y += lg[pi][1]; o.z += lg[pi][2]; o.w += lg[pi][3];
                    *(float4*)&at[p0 + pi][k0] = o;
                }
            }
            __syncthreads();
        }

        // ---------- softmax over k, in place; stores a' = softmax * s[p] ----------
        {
            const float sp = sS[s_p];
            float4 r0 = *(const float4*)&at[s_p][s_q << 3];
            float4 r1 = *(const float4*)&at[s_p][(s_q << 3) + 4];
            float L[8] = { r0.x * sp, r0.y * sp, r0.z * sp, r0.w * sp,
                           r1.x * sp, r1.y * sp, r1.z * sp, r1.w * sp };
            float m = L[0];
            #pragma unroll
            for (int j = 1; j < 8; ++j) m = fmaxf(m, L[j]);
            m = fmaxf(m, __shfl_xor(m, 1));
            m = fmaxf(m, __shfl_xor(m, 2));
            float e[8], s8 = 0.0f;
            #pragma unroll
            for (int j = 0; j < 8; ++j) {
                e[j] = exp2f((L[j] - m) * 1.4426950408889634f);
                s8 += e[j];
            }
            s8 += __shfl_xor(s8, 1);
            s8 += __shfl_xor(s8, 2);
            const float scl = sp / s8;
            *(float4*)&at[s_p][s_q << 3] =
                make_float4(e[0]*scl, e[1]*scl, e[2]*scl, e[3]*scl);
            *(float4*)&at[s_p][(s_q << 3) + 4] =
                make_float4(e[4]*scl, e[5]*scl, e[6]*scl, e[7]*scl);
        }
        __syncthreads();

        // ---------- asum partial (unscale a' via nS) ----------
        {
            float part = 0.0f;
            #pragma unroll
            for (int j = 0; j < 8; ++j) {
                int p = (u_ph << 3) + j;
                part += at[p][u_k] * nS[p];
            }
            asum_acc += part;
        }

        // ---------- agg: acc[k][d] += a'[k,p] * x_raw[d,p] ----------
        {
            const int k0 = a_kg << 2;
            const int rb = a_dg << 8;      // (4*a_dg)*64 words
            const int dm = a_dg & 15;
            #pragma unroll
            for (int pq = 0; pq < 16; ++pq) {
                const int fb = (pq ^ dm) << 2;
                float4 x0 = *(const float4*)(xl + rb + fb);
                float4 x1 = *(const float4*)(xl + rb + 64 + fb);
                float4 x2 = *(const float4*)(xl + rb + 128 + fb);
                float4 x3 = *(const float4*)(xl + rb + 192 + fb);
                float4 a0 = *(const float4*)&at[(pq << 2) + 0][k0];
                float4 a1 = *(const float4*)&at[(pq << 2) + 1][k0];
                float4 a2 = *(const float4*)&at[(pq << 2) + 2][k0];
                float4 a3 = *(const float4*)&at[(pq << 2) + 3][k0];
                float av[4][4] = {{a0.x,a0.y,a0.z,a0.w},{a1.x,a1.y,a1.z,a1.w},
                                  {a2.x,a2.y,a2.z,a2.w},{a3.x,a3.y,a3.z,a3.w}};
                float xv[4][4] = {{x0.x,x0.y,x0.z,x0.w},{x1.x,x1.y,x1.z,x1.w},
                                  {x2.x,x2.y,x2.z,x2.w},{x3.x,x3.y,x3.z,x3.w}};
                #pragma unroll
                for (int ki = 0; ki < 4; ++ki)
                    #pragma unroll
                    for (int di = 0; di < 4; ++di)
                        #pragma unroll
                        for (int j = 0; j < 4; ++j)
                            acc[ki][di] += av[j][ki] * xv[di][j];
            }
        }
        __syncthreads();   // tile done; next iteration overwrites xl/at
    }

    // ---------- write per-block partials ----------
    {
        const int base = ((n * S_SPL + ps) * K_CL) * D_CH;
        const int k0 = a_kg << 2, d0 = a_dg << 2;
        #pragma unroll
        for (int ki = 0; ki < 4; ++ki) {
            *(float4*)(aggp + base + (k0 + ki) * D_CH + d0) =
                make_float4(acc[ki][0], acc[ki][1], acc[ki][2], acc[ki][3]);
        }
    }
    asw[u_ph][u_k] = asum_acc;
    __syncthreads();
    if (tid < K_CL) {
        float s = 0.0f;
        #pragma unroll
        for (int j = 0; j < 8; ++j) s += asw[j][tid];
        asump[(n * S_SPL + ps) * K_CL + tid] = s;
    }
}

__global__ __launch_bounds__(256)
void netvlad_finish(const float* __restrict__ aggp, const float* __restrict__ asump,
                    const float* __restrict__ cen, float* __restrict__ out)
{
    __shared__ float red[K_CL][8];
    __shared__ float gw[4];
    __shared__ float gss;
    const int tid = threadIdx.x;
    const int n = blockIdx.x;
    const int k = tid >> 3;
    const int d0 = (tid & 7) << 4;

    float v[16];
    #pragma unroll
    for (int i = 0; i < 16; ++i) v[i] = 0.0f;
    float as = 0.0f;
    for (int q = 0; q < S_SPL; ++q) {
        const float* src = aggp + (((n * S_SPL + q) * K_CL) + k) * D_CH + d0;
        #pragma unroll
        for (int c = 0; c < 4; ++c) {
            float4 t4 = *(const float4*)(src + (c << 2));
            v[4*c+0] += t4.x; v[4*c+1] += t4.y; v[4*c+2] += t4.z; v[4*c+3] += t4.w;
        }
        as += asump[(n * S_SPL + q) * K_CL + k];
    }
    const float* cp = cen + k * D_CH + d0;
    float ssq = 0.0f;
    #pragma unroll
    for (int c = 0; c < 4; ++c) {
        float4 c4 = *(const float4*)(cp + (c << 2));
        v[4*c+0] -= as * c4.x;
        v[4*c+1] -= as * c4.y;
        v[4*c+2] -= as * c4.z;
        v[4*c+3] -= as * c4.w;
    }
    #pragma unroll
    for (int i = 0; i < 16; ++i) ssq += v[i] * v[i];
    red[k][tid & 7] = ssq;
    __syncthreads();
    float s2 = 0.0f;
    #pragma unroll
    for (int j = 0; j < 8; ++j) s2 += red[k][j];
    const float sc1 = 1.0f / fmaxf(sqrtf(s2), 1e-12f);
    #pragma unroll
    for (int i = 0; i < 16; ++i) v[i] *= sc1;
    float g = ssq * sc1 * sc1;
    #pragma unroll
    for (int off = 1; off < 64; off <<= 1) g += __shfl_xor(g, off);
    if ((tid & 63) == 0) gw[tid >> 6] = g;
    __syncthreads();
    if (tid == 0) gss = 1.0f / fmaxf(sqrtf(gw[0] + gw[1] + gw[2] + gw[3]), 1e-12f);
    __syncthreads();
    const float gsc = gss;
    float* op = out + (size_t)n * (K_CL * D_CH) + k * D_CH + d0;
    #pragma unroll
    for (int c = 0; c < 4; ++c) {
        *(float4*)(op + (c << 2)) =
            make_float4(v[4*c+0]*gsc, v[4*c+1]*gsc, v[4*c+2]*gsc, v[4*c+3]*gsc);
    }
}

extern "C" void kernel_launch(void* const* d_in, const int* in_sizes, int n_in,
                              void* d_out, int out_size, void* d_ws, size_t ws_size,
                              hipStream_t stream)
{
    const float* x   = (const float*)d_in[0];
    const float* w   = (const float*)d_in[1];
    const float* cen = (const float*)d_in[2];
    float* out = (float*)d_out;

    float* aggp  = (float*)d_ws;                                    // [64][8][32][128] = 8 MB
    float* asump = aggp + (size_t)N_IMG * S_SPL * K_CL * D_CH;      // [64][8][32] = 64 KB

    netvlad_main<<<N_IMG * S_SPL, 256, 0, stream>>>(x, w, aggp, asump);
    netvlad_finish<<<N_IMG, 256, 0, stream>>>(aggp, asump, cen, out);
}

// Round 5
// 64.632 us; speedup vs baseline: 1.9521x; 1.9521x over previous
//
#include <hip/hip_runtime.h>
#include <math.h>

#define N_IMG 64
#define D_CH  128
#define P_PIX 4096
#define K_CL  32
#define S_SPL 8
#define P_BLK (P_PIX / S_SPL)   // 512 pixels per block
#define TP    32                // pixels per tile
#define N_TILE (P_BLK / TP)     // 16 tiles

typedef __attribute__((ext_vector_type(8))) short bf16x8;
typedef __attribute__((ext_vector_type(4))) float f32x4;

#define LOG2E 1.4426950408889634f
#define MFMA(a, b, c) __builtin_amdgcn_mfma_f32_16x16x32_bf16(a, b, c, 0, 0, 0)

static __device__ __forceinline__ ushort f2bf(float f) {
    union { float f; unsigned u; } v; v.f = f;
    unsigned r = v.u + 0x7fffu + ((v.u >> 16) & 1u);
    return (ushort)(r >> 16);
}
static __device__ __forceinline__ float bf2f(ushort h) {
    union { unsigned u; float f; } v; v.u = ((unsigned)h) << 16; return v.f;
}
static __device__ __forceinline__ void cvt4(float a, float b, float c, float d,
                                            ushort4 &h, ushort4 &l) {
    h.x = f2bf(a); l.x = f2bf(a - bf2f(h.x));
    h.y = f2bf(b); l.y = f2bf(b - bf2f(h.y));
    h.z = f2bf(c); l.z = f2bf(c - bf2f(h.z));
    h.w = f2bf(d); l.w = f2bf(d - bf2f(h.w));
}

// LDS element-index layouts (ushort):
//   xT (p-major):  row p (0..31), 136 elems/row (272 B, pad kills stride conflicts)
//   xD (d-major):  row d (0..127), 40 elems/row (80 B)
//   a'  (k-major): row k (0..31), 40 elems/row
__global__ __launch_bounds__(256)
void netvlad_main(const float* __restrict__ x, const float* __restrict__ w,
                  float* __restrict__ aggp, float* __restrict__ asump)
{
    __shared__ __align__(16) ushort xTh[32 * 136], xTl[32 * 136];
    __shared__ __align__(16) ushort xDh[128 * 40], xDl[128 * 40];
    __shared__ __align__(16) ushort aph[32 * 40],  apl[32 * 40];
    __shared__ __align__(16) float  nrmbuf[32][32];
    __shared__ __align__(16) float  xch[4][64][4];
    __shared__ float sS[32];
    __shared__ float asw[4][16];

    const int tid = threadIdx.x;
    const int n   = blockIdx.x >> 3;
    const int ps  = blockIdx.x & 7;

    const int l   = tid & 63;
    const int wid = tid >> 6;
    const int q   = l >> 4;       // 16-lane group
    const int ln  = l & 15;
    const int mt  = wid >> 1;     // GEMM1 pixel m-tile (0/1)
    const int nt  = wid & 1;      // GEMM1/2 k n-tile (0/1)

    // ---- preload conv_w fragments into registers (hi/lo bf16), per wave's nt ----
    bf16x8 wh[4], wl[4];
    #pragma unroll
    for (int kk = 0; kk < 4; ++kk) {
        const float* wp = w + (nt * 16 + ln) * D_CH + kk * 32 + 8 * q;
        float4 wa = *(const float4*)wp;
        float4 wb = *(const float4*)(wp + 4);
        float f[8] = {wa.x, wa.y, wa.z, wa.w, wb.x, wb.y, wb.z, wb.w};
        #pragma unroll
        for (int i = 0; i < 8; ++i) {
            ushort hu = f2bf(f[i]);
            ushort lu = f2bf(f[i] - bf2f(hu));
            wh[kk][i] = (short)hu;
            wl[kk][i] = (short)lu;
        }
    }

    f32x4 acc2[2][2];   // aggT accumulators: [m-subtile(d)][n-tile(k)]
    #pragma unroll
    for (int a = 0; a < 2; ++a)
        #pragma unroll
        for (int b = 0; b < 2; ++b)
            acc2[a][b] = (f32x4){0.f, 0.f, 0.f, 0.f};
    float asacc = 0.0f;

    const float* xin = x + (size_t)n * D_CH * P_PIX + ps * P_BLK;

    for (int t = 0; t < N_TILE; ++t) {
        const float* xt = xin + t * TP;

        // ================= stage: global -> LDS (both layouts) + ssq ==========
        // xD path: thread covers 4 d-rows x 4 pixels (coalesced float4)
        float4 xv[4];
        #pragma unroll
        for (int it = 0; it < 4; ++it) {
            int d = it * 32 + (tid >> 3);
            xv[it] = *(const float4*)(xt + d * P_PIX + 4 * (tid & 7));
        }
        // xT path: thread covers 16 d at one pixel (64B-chunk coalesced b32)
        const int pT = tid & 31;
        const int dbase = (tid >> 5) * 16;
        float tv[16];
        #pragma unroll
        for (int j = 0; j < 16; ++j)
            tv[j] = xt[(size_t)(dbase + j) * P_PIX + pT];

        float s0 = 0.f, s1 = 0.f, s2 = 0.f, s3 = 0.f;
        #pragma unroll
        for (int it = 0; it < 4; ++it) {
            int d = it * 32 + (tid >> 3);
            ushort4 h, lo;
            cvt4(xv[it].x, xv[it].y, xv[it].z, xv[it].w, h, lo);
            *(ushort4*)&xDh[d * 40 + 4 * (tid & 7)] = h;
            *(ushort4*)&xDl[d * 40 + 4 * (tid & 7)] = lo;
            s0 += xv[it].x * xv[it].x; s1 += xv[it].y * xv[it].y;
            s2 += xv[it].z * xv[it].z; s3 += xv[it].w * xv[it].w;
        }
        *(float4*)&nrmbuf[tid >> 3][4 * (tid & 7)] = make_float4(s0, s1, s2, s3);

        #pragma unroll
        for (int c = 0; c < 4; ++c) {
            ushort4 h, lo;
            cvt4(tv[4*c+0], tv[4*c+1], tv[4*c+2], tv[4*c+3], h, lo);
            *(ushort4*)&xTh[pT * 136 + dbase + 4 * c] = h;
            *(ushort4*)&xTl[pT * 136 + dbase + 4 * c] = lo;
        }
        __syncthreads();                                   // b1: tiles staged

        // ---- finalize 1/||x|| (8 lanes per wave), overlapped with GEMM1 ----
        if ((tid & 63) < 8) {
            int p = (tid >> 6) * 8 + (tid & 7);
            float ssq = 0.f;
            #pragma unroll
            for (int j = 0; j < 32; ++j) ssq += nrmbuf[j][p];
            sS[p] = 1.0f / fmaxf(sqrtf(ssq), 1e-12f);
        }

        // ================= GEMM1: logits (p x k), contract d ==================
        f32x4 acc1 = (f32x4){0.f, 0.f, 0.f, 0.f};
        #pragma unroll
        for (int kk = 0; kk < 4; ++kk) {
            int ia = (mt * 16 + ln) * 136 + kk * 32 + 8 * q;
            bf16x8 Ah = *(const bf16x8*)&xTh[ia];
            bf16x8 Al = *(const bf16x8*)&xTl[ia];
            acc1 = MFMA(Ah, wh[kk], acc1);
            acc1 = MFMA(Ah, wl[kk], acc1);
            acc1 = MFMA(Al, wh[kk], acc1);
        }
        __syncthreads();                                   // b2: sS ready

        // ================= softmax over k (in-register, no max-sub) ===========
        // lane holds logits for pixels p = mt*16+4q+r, k = nt*16+ln
        float4 sp4 = *(const float4*)&sS[mt * 16 + 4 * q];
        float e[4], s[4];
        e[0] = exp2f(acc1[0] * sp4.x * LOG2E);
        e[1] = exp2f(acc1[1] * sp4.y * LOG2E);
        e[2] = exp2f(acc1[2] * sp4.z * LOG2E);
        e[3] = exp2f(acc1[3] * sp4.w * LOG2E);
        #pragma unroll
        for (int r = 0; r < 4; ++r) {
            s[r] = e[r];
            s[r] += __shfl_xor(s[r], 1);
            s[r] += __shfl_xor(s[r], 2);
            s[r] += __shfl_xor(s[r], 4);
            s[r] += __shfl_xor(s[r], 8);
        }
        *(float4*)&xch[wid][l][0] = make_float4(s[0], s[1], s[2], s[3]);
        __syncthreads();                                   // b3: partial sums
        {
            float4 po = *(const float4*)&xch[wid ^ 1][l][0];
            float st[4] = {s[0] + po.x, s[1] + po.y, s[2] + po.z, s[3] + po.w};
            float sm[4], ap[4];
            #pragma unroll
            for (int r = 0; r < 4; ++r) sm[r] = e[r] / st[r];
            asacc += sm[0] + sm[1] + sm[2] + sm[3];
            ap[0] = sm[0] * sp4.x; ap[1] = sm[1] * sp4.y;
            ap[2] = sm[2] * sp4.z; ap[3] = sm[3] * sp4.w;
            ushort4 h, lo;
            cvt4(ap[0], ap[1], ap[2], ap[3], h, lo);
            int ib = (nt * 16 + ln) * 40 + mt * 16 + 4 * q;
            *(ushort4*)&aph[ib] = h;
            *(ushort4*)&apl[ib] = lo;
        }
        __syncthreads();                                   // b4: a' ready

        // ================= GEMM2: aggT (d x k), contract p ====================
        bf16x8 A2h[2], A2l[2], B2h[2], B2l[2];
        #pragma unroll
        for (int m2 = 0; m2 < 2; ++m2) {
            int ia = ((2 * wid + m2) * 16 + ln) * 40 + 8 * q;
            A2h[m2] = *(const bf16x8*)&xDh[ia];
            A2l[m2] = *(const bf16x8*)&xDl[ia];
        }
        #pragma unroll
        for (int n2 = 0; n2 < 2; ++n2) {
            int ib = (n2 * 16 + ln) * 40 + 8 * q;
            B2h[n2] = *(const bf16x8*)&aph[ib];
            B2l[n2] = *(const bf16x8*)&apl[ib];
        }
        #pragma unroll
        for (int m2 = 0; m2 < 2; ++m2)
            #pragma unroll
            for (int n2 = 0; n2 < 2; ++n2) {
                acc2[m2][n2] = MFMA(A2h[m2], B2h[n2], acc2[m2][n2]);
                acc2[m2][n2] = MFMA(A2h[m2], B2l[n2], acc2[m2][n2]);
                acc2[m2][n2] = MFMA(A2l[m2], B2h[n2], acc2[m2][n2]);
            }
        __syncthreads();                                   // b5: end of tile
    }

    // ================= epilogue: partials to workspace =======================
    const int base = ((n * S_SPL + ps) * K_CL) * D_CH;
    #pragma unroll
    for (int m2 = 0; m2 < 2; ++m2)
        #pragma unroll
        for (int n2 = 0; n2 < 2; ++n2) {
            int k = n2 * 16 + ln;
            #pragma unroll
            for (int r = 0; r < 4; ++r) {
                int d = (2 * wid + m2) * 16 + 4 * q + r;
                aggp[base + k * D_CH + d] = acc2[m2][n2][r];
            }
        }
    asacc += __shfl_xor(asacc, 16);
    asacc += __shfl_xor(asacc, 32);
    if (l < 16) asw[wid][l] = asacc;
    __syncthreads();
    if (tid < K_CL)
        asump[(n * S_SPL + ps) * K_CL + tid] =
            asw[tid >> 4][tid & 15] + asw[(tid >> 4) + 2][tid & 15];
}

__global__ __launch_bounds__(256)
void netvlad_finish(const float* __restrict__ aggp, const float* __restrict__ asump,
                    const float* __restrict__ cen, float* __restrict__ out)
{
    __shared__ float red[K_CL][8];
    __shared__ float gw[4];
    __shared__ float gss;
    const int tid = threadIdx.x;
    const int n = blockIdx.x;
    const int k = tid >> 3;
    const int d0 = (tid & 7) << 4;

    float v[16];
    #pragma unroll
    for (int i = 0; i < 16; ++i) v[i] = 0.0f;
    float as = 0.0f;
    for (int qq = 0; qq < S_SPL; ++qq) {
        const float* src = aggp + (((n * S_SPL + qq) * K_CL) + k) * D_CH + d0;
        #pragma unroll
        for (int c = 0; c < 4; ++c) {
            float4 t4 = *(const float4*)(src + (c << 2));
            v[4*c+0] += t4.x; v[4*c+1] += t4.y; v[4*c+2] += t4.z; v[4*c+3] += t4.w;
        }
        as += asump[(n * S_SPL + qq) * K_CL + k];
    }
    const float* cp = cen + k * D_CH + d0;
    float ssq = 0.0f;
    #pragma unroll
    for (int c = 0; c < 4; ++c) {
        float4 c4 = *(const float4*)(cp + (c << 2));
        v[4*c+0] -= as * c4.x;
        v[4*c+1] -= as * c4.y;
        v[4*c+2] -= as * c4.z;
        v[4*c+3] -= as * c4.w;
    }
    #pragma unroll
    for (int i = 0; i < 16; ++i) ssq += v[i] * v[i];
    red[k][tid & 7] = ssq;
    __syncthreads();
    float s2 = 0.0f;
    #pragma unroll
    for (int j = 0; j < 8; ++j) s2 += red[k][j];
    const float sc1 = 1.0f / fmaxf(sqrtf(s2), 1e-12f);
    #pragma unroll
    for (int i = 0; i < 16; ++i) v[i] *= sc1;
    float g = ssq * sc1 * sc1;
    #pragma unroll
    for (int off = 1; off < 64; off <<= 1) g += __shfl_xor(g, off);
    if ((tid & 63) == 0) gw[tid >> 6] = g;
    __syncthreads();
    if (tid == 0) gss = 1.0f / fmaxf(sqrtf(gw[0] + gw[1] + gw[2] + gw[3]), 1e-12f);
    __syncthreads();
    const float gsc = gss;
    float* op = out + (size_t)n * (K_CL * D_CH) + k * D_CH + d0;
    #pragma unroll
    for (int c = 0; c < 4; ++c) {
        *(float4*)(op + (c << 2)) =
            make_float4(v[4*c+0]*gsc, v[4*c+1]*gsc, v[4*c+2]*gsc, v[4*c+3]*gsc);
    }
}

extern "C" void kernel_launch(void* const* d_in, const int* in_sizes, int n_in,
                              void* d_out, int out_size, void* d_ws, size_t ws_size,
                              hipStream_t stream)
{
    const float* x   = (const float*)d_in[0];
    const float* w   = (const float*)d_in[1];
    const float* cen = (const float*)d_in[2];
    float* out = (float*)d_out;

    float* aggp  = (float*)d_ws;                                    // [64][8][32][128] = 8 MB
    float* asump = aggp + (size_t)N_IMG * S_SPL * K_CL * D_CH;      // [64][8][32]

    netvlad_main<<<N_IMG * S_SPL, 256, 0, stream>>>(x, w, aggp, asump);
    netvlad_finish<<<N_IMG, 256, 0, stream>>>(aggp, asump, cen, out);
}

// Round 6
// 57.403 us; speedup vs baseline: 2.1979x; 1.1259x over previous
//
#include <hip/hip_runtime.h>
#include <math.h>

#define N_IMG 64
#define D_CH  128
#define P_PIX 4096
#define K_CL  32
#define S_SPL 8
#define P_BLK (P_PIX / S_SPL)   // 512 pixels per block
#define TP    32                // pixels per tile
#define N_TILE (P_BLK / TP)     // 16 tiles

typedef __attribute__((ext_vector_type(8))) short bf16x8;
typedef __attribute__((ext_vector_type(4))) float f32x4;

#define MFMA(a, b, c) __builtin_amdgcn_mfma_f32_16x16x32_bf16(a, b, c, 0, 0, 0)

// Dekker-style truncation split: f = hi + lo + O(2^-17 |f|), hi/lo bf16.
// hi = trunc16(f); lo = trunc16(f - hi)  (f - hi is fp32-exact).
static __device__ __forceinline__ void split4t(float a, float b, float c, float d,
                                               ushort4 &h, ushort4 &l) {
    unsigned ua = __float_as_uint(a), ub = __float_as_uint(b);
    unsigned uc = __float_as_uint(c), ud = __float_as_uint(d);
    h.x = (ushort)(ua >> 16); h.y = (ushort)(ub >> 16);
    h.z = (ushort)(uc >> 16); h.w = (ushort)(ud >> 16);
    float ra = a - __uint_as_float(ua & 0xffff0000u);
    float rb = b - __uint_as_float(ub & 0xffff0000u);
    float rc = c - __uint_as_float(uc & 0xffff0000u);
    float rd = d - __uint_as_float(ud & 0xffff0000u);
    l.x = (ushort)(__float_as_uint(ra) >> 16);
    l.y = (ushort)(__float_as_uint(rb) >> 16);
    l.z = (ushort)(__float_as_uint(rc) >> 16);
    l.w = (ushort)(__float_as_uint(rd) >> 16);
}

// LDS element-index layouts (ushort):
//   xT (p-major):  row p (0..31), 136 elems/row (272 B, pad kills stride conflicts)
//   xD (d-major):  row d (0..127), 40 elems/row (80 B)
//   a'  (k-major): row k (0..31), 40 elems/row
__global__ __launch_bounds__(256)
void netvlad_main(const float* __restrict__ x, const float* __restrict__ w,
                  float* __restrict__ aggp, float* __restrict__ asump)
{
    __shared__ __align__(16) ushort xTh[32 * 136], xTl[32 * 136];
    __shared__ __align__(16) ushort xDh[128 * 40], xDl[128 * 40];
    __shared__ __align__(16) ushort aph[32 * 40],  apl[32 * 40];
    __shared__ __align__(16) float  nrmbuf[32][32];
    __shared__ __align__(16) float  xch[4][64][4];
    __shared__ float sS[32];
    __shared__ float asw[4][16];

    const int tid = threadIdx.x;
    const int n   = blockIdx.x >> 3;
    const int ps  = blockIdx.x & 7;

    const int l   = tid & 63;
    const int wid = tid >> 6;
    const int q   = l >> 4;       // 16-lane group
    const int ln  = l & 15;
    const int mt  = wid >> 1;     // GEMM1 pixel m-tile (0/1)
    const int nt  = wid & 1;      // GEMM1/2 k n-tile (0/1)

    // ---- preload conv_w fragments into registers (hi/lo bf16), per wave's nt ----
    bf16x8 wh[4], wl[4];
    #pragma unroll
    for (int kk = 0; kk < 4; ++kk) {
        const float* wp = w + (nt * 16 + ln) * D_CH + kk * 32 + 8 * q;
        float4 wa = *(const float4*)wp;
        float4 wb = *(const float4*)(wp + 4);
        ushort4 h1, l1, h2, l2;
        split4t(wa.x, wa.y, wa.z, wa.w, h1, l1);
        split4t(wb.x, wb.y, wb.z, wb.w, h2, l2);
        wh[kk][0] = (short)h1.x; wh[kk][1] = (short)h1.y; wh[kk][2] = (short)h1.z; wh[kk][3] = (short)h1.w;
        wh[kk][4] = (short)h2.x; wh[kk][5] = (short)h2.y; wh[kk][6] = (short)h2.z; wh[kk][7] = (short)h2.w;
        wl[kk][0] = (short)l1.x; wl[kk][1] = (short)l1.y; wl[kk][2] = (short)l1.z; wl[kk][3] = (short)l1.w;
        wl[kk][4] = (short)l2.x; wl[kk][5] = (short)l2.y; wl[kk][6] = (short)l2.z; wl[kk][7] = (short)l2.w;
    }

    f32x4 acc2[2][2];   // aggT accumulators: [m-subtile(d)][n-tile(k)]
    #pragma unroll
    for (int a = 0; a < 2; ++a)
        #pragma unroll
        for (int b = 0; b < 2; ++b)
            acc2[a][b] = (f32x4){0.f, 0.f, 0.f, 0.f};
    float asacc = 0.0f;

    const float* xin = x + (size_t)n * D_CH * P_PIX + ps * P_BLK;

    const int pT    = tid & 31;
    const int dbase = (tid >> 5) * 16;

    // ---- prologue: load tile 0 into registers ----
    float4 xv[4];
    float  tv[16];
    {
        const float* xt = xin;
        #pragma unroll
        for (int it = 0; it < 4; ++it) {
            int d = it * 32 + (tid >> 3);
            xv[it] = *(const float4*)(xt + d * P_PIX + 4 * (tid & 7));
        }
        #pragma unroll
        for (int j = 0; j < 16; ++j)
            tv[j] = xt[(size_t)(dbase + j) * P_PIX + pT];
    }

    for (int t = 0; t < N_TILE; ++t) {
        // ================= stage: regs -> LDS (both layouts) + ssq ============
        float s0 = 0.f, s1 = 0.f, s2 = 0.f, s3 = 0.f;
        #pragma unroll
        for (int it = 0; it < 4; ++it) {
            int d = it * 32 + (tid >> 3);
            ushort4 h, lo;
            split4t(xv[it].x, xv[it].y, xv[it].z, xv[it].w, h, lo);
            *(ushort4*)&xDh[d * 40 + 4 * (tid & 7)] = h;
            *(ushort4*)&xDl[d * 40 + 4 * (tid & 7)] = lo;
            s0 += xv[it].x * xv[it].x; s1 += xv[it].y * xv[it].y;
            s2 += xv[it].z * xv[it].z; s3 += xv[it].w * xv[it].w;
        }
        *(float4*)&nrmbuf[tid >> 3][4 * (tid & 7)] = make_float4(s0, s1, s2, s3);

        #pragma unroll
        for (int c = 0; c < 4; ++c) {
            ushort4 h, lo;
            split4t(tv[4*c+0], tv[4*c+1], tv[4*c+2], tv[4*c+3], h, lo);
            *(ushort4*)&xTh[pT * 136 + dbase + 4 * c] = h;
            *(ushort4*)&xTl[pT * 136 + dbase + 4 * c] = lo;
        }

        // ---- prefetch tile t+1 into the (now consumed) registers ----
        if (t + 1 < N_TILE) {
            const float* xt2 = xin + (t + 1) * TP;
            #pragma unroll
            for (int it = 0; it < 4; ++it) {
                int d = it * 32 + (tid >> 3);
                xv[it] = *(const float4*)(xt2 + d * P_PIX + 4 * (tid & 7));
            }
            #pragma unroll
            for (int j = 0; j < 16; ++j)
                tv[j] = xt2[(size_t)(dbase + j) * P_PIX + pT];
        }
        __syncthreads();                                   // b1: tiles staged

        // ---- finalize 1/||x|| (8 lanes per wave), overlapped with GEMM1 ----
        if ((tid & 63) < 8) {
            int p = (tid >> 6) * 8 + (tid & 7);
            float ssq = 0.f;
            #pragma unroll
            for (int j = 0; j < 32; ++j) ssq += nrmbuf[j][p];
            sS[p] = 1.0f / fmaxf(sqrtf(ssq), 1e-12f);
        }

        // ================= GEMM1: logits (p x k), contract d ==================
        f32x4 acc1 = (f32x4){0.f, 0.f, 0.f, 0.f};
        #pragma unroll
        for (int kk = 0; kk < 4; ++kk) {
            int ia = (mt * 16 + ln) * 136 + kk * 32 + 8 * q;
            bf16x8 Ah = *(const bf16x8*)&xTh[ia];
            bf16x8 Al = *(const bf16x8*)&xTl[ia];
            acc1 = MFMA(Ah, wh[kk], acc1);
            acc1 = MFMA(Ah, wl[kk], acc1);
            acc1 = MFMA(Al, wh[kk], acc1);
        }
        __syncthreads();                                   // b2: sS ready

        // ================= softmax over k (in-register, no max-sub) ===========
        // lane holds logits for pixels p = mt*16+4q+r, k = nt*16+ln
        float4 sp4 = *(const float4*)&sS[mt * 16 + 4 * q];
        float e[4], s[4];
        e[0] = __builtin_expf(acc1[0] * sp4.x);
        e[1] = __builtin_expf(acc1[1] * sp4.y);
        e[2] = __builtin_expf(acc1[2] * sp4.z);
        e[3] = __builtin_expf(acc1[3] * sp4.w);
        #pragma unroll
        for (int r = 0; r < 4; ++r) {
            s[r] = e[r];
            s[r] += __shfl_xor(s[r], 1);
            s[r] += __shfl_xor(s[r], 2);
            s[r] += __shfl_xor(s[r], 4);
            s[r] += __shfl_xor(s[r], 8);
        }
        *(float4*)&xch[wid][l][0] = make_float4(s[0], s[1], s[2], s[3]);
        __syncthreads();                                   // b3: partial sums
        {
            float4 po = *(const float4*)&xch[wid ^ 1][l][0];
            float rt[4];
            rt[0] = __builtin_amdgcn_rcpf(s[0] + po.x);
            rt[1] = __builtin_amdgcn_rcpf(s[1] + po.y);
            rt[2] = __builtin_amdgcn_rcpf(s[2] + po.z);
            rt[3] = __builtin_amdgcn_rcpf(s[3] + po.w);
            float sm[4], ap[4];
            #pragma unroll
            for (int r = 0; r < 4; ++r) sm[r] = e[r] * rt[r];
            asacc += sm[0] + sm[1] + sm[2] + sm[3];
            ap[0] = sm[0] * sp4.x; ap[1] = sm[1] * sp4.y;
            ap[2] = sm[2] * sp4.z; ap[3] = sm[3] * sp4.w;
            ushort4 h, lo;
            split4t(ap[0], ap[1], ap[2], ap[3], h, lo);
            int ib = (nt * 16 + ln) * 40 + mt * 16 + 4 * q;
            *(ushort4*)&aph[ib] = h;
            *(ushort4*)&apl[ib] = lo;
        }
        __syncthreads();                                   // b4: a' ready

        // ================= GEMM2: aggT (d x k), contract p ====================
        bf16x8 A2h[2], A2l[2], B2h[2], B2l[2];
        #pragma unroll
        for (int m2 = 0; m2 < 2; ++m2) {
            int ia = ((2 * wid + m2) * 16 + ln) * 40 + 8 * q;
            A2h[m2] = *(const bf16x8*)&xDh[ia];
            A2l[m2] = *(const bf16x8*)&xDl[ia];
        }
        #pragma unroll
        for (int n2 = 0; n2 < 2; ++n2) {
            int ib = (n2 * 16 + ln) * 40 + 8 * q;
            B2h[n2] = *(const bf16x8*)&aph[ib];
            B2l[n2] = *(const bf16x8*)&apl[ib];
        }
        #pragma unroll
        for (int m2 = 0; m2 < 2; ++m2)
            #pragma unroll
            for (int n2 = 0; n2 < 2; ++n2) {
                acc2[m2][n2] = MFMA(A2h[m2], B2h[n2], acc2[m2][n2]);
                acc2[m2][n2] = MFMA(A2h[m2], B2l[n2], acc2[m2][n2]);
                acc2[m2][n2] = MFMA(A2l[m2], B2h[n2], acc2[m2][n2]);
            }
        __syncthreads();                                   // b5: end of tile
    }

    // ================= epilogue: partials to workspace =======================
    const int base = ((n * S_SPL + ps) * K_CL) * D_CH;
    #pragma unroll
    for (int m2 = 0; m2 < 2; ++m2)
        #pragma unroll
        for (int n2 = 0; n2 < 2; ++n2) {
            int k = n2 * 16 + ln;
            #pragma unroll
            for (int r = 0; r < 4; ++r) {
                int d = (2 * wid + m2) * 16 + 4 * q + r;
                aggp[base + k * D_CH + d] = acc2[m2][n2][r];
            }
        }
    asacc += __shfl_xor(asacc, 16);
    asacc += __shfl_xor(asacc, 32);
    if (l < 16) asw[wid][l] = asacc;
    __syncthreads();
    if (tid < K_CL)
        asump[(n * S_SPL + ps) * K_CL + tid] =
            asw[tid >> 4][tid & 15] + asw[(tid >> 4) + 2][tid & 15];
}

__global__ __launch_bounds__(256)
void netvlad_finish(const float* __restrict__ aggp, const float* __restrict__ asump,
                    const float* __restrict__ cen, float* __restrict__ out)
{
    __shared__ float red[K_CL][8];
    __shared__ float gw[4];
    __shared__ float gss;
    const int tid = threadIdx.x;
    const int n = blockIdx.x;
    const int k = tid >> 3;
    const int d0 = (tid & 7) << 4;

    float v[16];
    #pragma unroll
    for (int i = 0; i < 16; ++i) v[i] = 0.0f;
    float as = 0.0f;
    for (int qq = 0; qq < S_SPL; ++qq) {
        const float* src = aggp + (((n * S_SPL + qq) * K_CL) + k) * D_CH + d0;
        #pragma unroll
        for (int c = 0; c < 4; ++c) {
            float4 t4 = *(const float4*)(src + (c << 2));
            v[4*c+0] += t4.x; v[4*c+1] += t4.y; v[4*c+2] += t4.z; v[4*c+3] += t4.w;
        }
        as += asump[(n * S_SPL + qq) * K_CL + k];
    }
    const float* cp = cen + k * D_CH + d0;
    float ssq = 0.0f;
    #pragma unroll
    for (int c = 0; c < 4; ++c) {
        float4 c4 = *(const float4*)(cp + (c << 2));
        v[4*c+0] -= as * c4.x;
        v[4*c+1] -= as * c4.y;
        v[4*c+2] -= as * c4.z;
        v[4*c+3] -= as * c4.w;
    }
    #pragma unroll
    for (int i = 0; i < 16; ++i) ssq += v[i] * v[i];
    red[k][tid & 7] = ssq;
    __syncthreads();
    float s2 = 0.0f;
    #pragma unroll
    for (int j = 0; j < 8; ++j) s2 += red[k][j];
    const float sc1 = 1.0f / fmaxf(sqrtf(s2), 1e-12f);
    #pragma unroll
    for (int i = 0; i < 16; ++i) v[i] *= sc1;
    float g = ssq * sc1 * sc1;
    #pragma unroll
    for (int off = 1; off < 64; off <<= 1) g += __shfl_xor(g, off);
    if ((tid & 63) == 0) gw[tid >> 6] = g;
    __syncthreads();
    if (tid == 0) gss = 1.0f / fmaxf(sqrtf(gw[0] + gw[1] + gw[2] + gw[3]), 1e-12f);
    __syncthreads();
    const float gsc = gss;
    float* op = out + (size_t)n * (K_CL * D_CH) + k * D_CH + d0;
    #pragma unroll
    for (int c = 0; c < 4; ++c) {
        *(float4*)(op + (c << 2)) =
            make_float4(v[4*c+0]*gsc, v[4*c+1]*gsc, v[4*c+2]*gsc, v[4*c+3]*gsc);
    }
}

extern "C" void kernel_launch(void* const* d_in, const int* in_sizes, int n_in,
                              void* d_out, int out_size, void* d_ws, size_t ws_size,
                              hipStream_t stream)
{
    const float* x   = (const float*)d_in[0];
    const float* w   = (const float*)d_in[1];
    const float* cen = (const float*)d_in[2];
    float* out = (float*)d_out;

    float* aggp  = (float*)d_ws;                                    // [64][8][32][128] = 8 MB
    float* asump = aggp + (size_t)N_IMG * S_SPL * K_CL * D_CH;      // [64][8][32]

    netvlad_main<<<N_IMG * S_SPL, 256, 0, stream>>>(x, w, aggp, asump);
    netvlad_finish<<<N_IMG, 256, 0, stream>>>(aggp, asump, cen, out);
}

// Round 8
// 52.819 us; speedup vs baseline: 2.3887x; 1.0868x over previous
//
#include <hip/hip_runtime.h>
#include <math.h>

#define N_IMG 64
#define D_CH  128
#define P_PIX 4096
#define K_CL  32
#define S_SPL 8
#define P_BLK (P_PIX / S_SPL)   // 512 pixels per block
#define TP    32                // pixels per tile
#define N_TILE (P_BLK / TP)     // 16 tiles

typedef __attribute__((ext_vector_type(8))) short bf16x8;
typedef __attribute__((ext_vector_type(4))) float f32x4;

#define MFMA(a, b, c) __builtin_amdgcn_mfma_f32_16x16x32_bf16(a, b, c, 0, 0, 0)

// Dekker-style truncation split: f = hi + lo + O(2^-17 |f|), hi/lo bf16.
static __device__ __forceinline__ void split4t(float a, float b, float c, float d,
                                               ushort4 &h, ushort4 &l) {
    unsigned ua = __float_as_uint(a), ub = __float_as_uint(b);
    unsigned uc = __float_as_uint(c), ud = __float_as_uint(d);
    h.x = (ushort)(ua >> 16); h.y = (ushort)(ub >> 16);
    h.z = (ushort)(uc >> 16); h.w = (ushort)(ud >> 16);
    float ra = a - __uint_as_float(ua & 0xffff0000u);
    float rb = b - __uint_as_float(ub & 0xffff0000u);
    float rc = c - __uint_as_float(uc & 0xffff0000u);
    float rd = d - __uint_as_float(ud & 0xffff0000u);
    l.x = (ushort)(__float_as_uint(ra) >> 16);
    l.y = (ushort)(__float_as_uint(rb) >> 16);
    l.z = (ushort)(__float_as_uint(rc) >> 16);
    l.w = (ushort)(__float_as_uint(rd) >> 16);
}

// LDS element-index layouts (ushort):
//   xT (p-major):  row p (0..31), 136 elems/row (272 B, pad kills stride conflicts)
//   xD (d-major):  row d (0..127), 40 elems/row (80 B)
//   a'  (k-major): row k (0..31), 40 elems/row
__global__ __launch_bounds__(256)
void netvlad_main(const float* __restrict__ x, const float* __restrict__ w,
                  float* __restrict__ aggp, float* __restrict__ asump)
{
    __shared__ __align__(16) ushort xTh[32 * 136], xTl[32 * 136];
    __shared__ __align__(16) ushort xDh[128 * 40], xDl[128 * 40];
    __shared__ __align__(16) ushort aph[32 * 40],  apl[32 * 40];
    __shared__ __align__(16) float  xch[4][64][4];
    __shared__ float pbuf[4][32];   // per-wave ssq partials (pixel-indexed)
    __shared__ float sS[32];
    __shared__ float asw[4][16];

    const int tid = threadIdx.x;
    const int n   = blockIdx.x >> 3;
    const int ps  = blockIdx.x & 7;

    const int l   = tid & 63;
    const int wid = tid >> 6;
    const int q   = l >> 4;       // 16-lane group
    const int ln  = l & 15;
    const int mt  = wid >> 1;     // GEMM1 pixel m-tile (0/1)
    const int nt  = wid & 1;      // GEMM1/2 k n-tile (0/1)

    // ---- preload conv_w fragments into registers (hi/lo bf16), per wave's nt ----
    bf16x8 wh[4], wl[4];
    #pragma unroll
    for (int kk = 0; kk < 4; ++kk) {
        const float* wp = w + (nt * 16 + ln) * D_CH + kk * 32 + 8 * q;
        float4 wa = *(const float4*)wp;
        float4 wb = *(const float4*)(wp + 4);
        ushort4 h1, l1, h2, l2;
        split4t(wa.x, wa.y, wa.z, wa.w, h1, l1);
        split4t(wb.x, wb.y, wb.z, wb.w, h2, l2);
        wh[kk][0] = (short)h1.x; wh[kk][1] = (short)h1.y; wh[kk][2] = (short)h1.z; wh[kk][3] = (short)h1.w;
        wh[kk][4] = (short)h2.x; wh[kk][5] = (short)h2.y; wh[kk][6] = (short)h2.z; wh[kk][7] = (short)h2.w;
        wl[kk][0] = (short)l1.x; wl[kk][1] = (short)l1.y; wl[kk][2] = (short)l1.z; wl[kk][3] = (short)l1.w;
        wl[kk][4] = (short)l2.x; wl[kk][5] = (short)l2.y; wl[kk][6] = (short)l2.z; wl[kk][7] = (short)l2.w;
    }

    f32x4 acc2[2][2];   // aggT accumulators: [m-subtile(d)][n-tile(k)]
    #pragma unroll
    for (int a = 0; a < 2; ++a)
        #pragma unroll
        for (int b = 0; b < 2; ++b)
            acc2[a][b] = (f32x4){0.f, 0.f, 0.f, 0.f};
    float asacc = 0.0f;

    const float* xin = x + (size_t)n * D_CH * P_PIX + ps * P_BLK;

    const int pT    = tid & 31;
    const int dbase = (tid >> 5) * 16;

    // ---- prologue: load tile 0 into registers ----
    float4 xv[4];
    float  tv[16];
    {
        const float* xt = xin;
        #pragma unroll
        for (int it = 0; it < 4; ++it) {
            int d = it * 32 + (tid >> 3);
            xv[it] = *(const float4*)(xt + d * P_PIX + 4 * (tid & 7));
        }
        #pragma unroll
        for (int j = 0; j < 16; ++j)
            tv[j] = xt[(size_t)(dbase + j) * P_PIX + pT];
    }

    for (int t = 0; t < N_TILE; ++t) {
        // ================= stage: regs -> LDS (both layouts) ==================
        #pragma unroll
        for (int it = 0; it < 4; ++it) {
            int d = it * 32 + (tid >> 3);
            ushort4 h, lo;
            split4t(xv[it].x, xv[it].y, xv[it].z, xv[it].w, h, lo);
            *(ushort4*)&xDh[d * 40 + 4 * (tid & 7)] = h;
            *(ushort4*)&xDl[d * 40 + 4 * (tid & 7)] = lo;
        }

        // xT staging + per-pixel ssq partial from tv registers
        float sq = 0.f;
        #pragma unroll
        for (int c = 0; c < 4; ++c) {
            ushort4 h, lo;
            split4t(tv[4*c+0], tv[4*c+1], tv[4*c+2], tv[4*c+3], h, lo);
            *(ushort4*)&xTh[pT * 136 + dbase + 4 * c] = h;
            *(ushort4*)&xTl[pT * 136 + dbase + 4 * c] = lo;
            sq += tv[4*c+0]*tv[4*c+0] + tv[4*c+1]*tv[4*c+1]
                + tv[4*c+2]*tv[4*c+2] + tv[4*c+3]*tv[4*c+3];
        }
        // reduce the wave's two d-chunks (lanes l and l^32 share pT)
        sq += __shfl_xor(sq, 32);
        if (l < 32) pbuf[wid][pT] = sq;

        // ---- prefetch tile t+1 into the (now consumed) registers ----
        if (t + 1 < N_TILE) {
            const float* xt2 = xin + (t + 1) * TP;
            #pragma unroll
            for (int it = 0; it < 4; ++it) {
                int d = it * 32 + (tid >> 3);
                xv[it] = *(const float4*)(xt2 + d * P_PIX + 4 * (tid & 7));
            }
            #pragma unroll
            for (int j = 0; j < 16; ++j)
                tv[j] = xt2[(size_t)(dbase + j) * P_PIX + pT];
        }
        __syncthreads();                                   // b1: tiles staged

        // ---- finalize 1/||x|| (wave 0 only), overlapped with GEMM1 ----
        if (tid < 32) {
            float ssq = pbuf[0][tid] + pbuf[1][tid] + pbuf[2][tid] + pbuf[3][tid];
            sS[tid] = 1.0f / fmaxf(sqrtf(ssq), 1e-12f);
        }

        // ================= GEMM1: logits (p x k), contract d ==================
        f32x4 acc1 = (f32x4){0.f, 0.f, 0.f, 0.f};
        #pragma unroll
        for (int kk = 0; kk < 4; ++kk) {
            int ia = (mt * 16 + ln) * 136 + kk * 32 + 8 * q;
            bf16x8 Ah = *(const bf16x8*)&xTh[ia];
            bf16x8 Al = *(const bf16x8*)&xTl[ia];
            acc1 = MFMA(Ah, wh[kk], acc1);
            acc1 = MFMA(Ah, wl[kk], acc1);
            acc1 = MFMA(Al, wh[kk], acc1);
        }
        __syncthreads();                                   // b2: sS ready

        // ================= softmax over k (in-register, no max-sub) ===========
        // lane holds logits for pixels p = mt*16+4q+r, k = nt*16+ln
        float4 sp4 = *(const float4*)&sS[mt * 16 + 4 * q];
        float e[4], s[4];
        e[0] = __builtin_expf(acc1[0] * sp4.x);
        e[1] = __builtin_expf(acc1[1] * sp4.y);
        e[2] = __builtin_expf(acc1[2] * sp4.z);
        e[3] = __builtin_expf(acc1[3] * sp4.w);
        #pragma unroll
        for (int r = 0; r < 4; ++r) {
            s[r] = e[r];
            s[r] += __shfl_xor(s[r], 1);
            s[r] += __shfl_xor(s[r], 2);
            s[r] += __shfl_xor(s[r], 4);
            s[r] += __shfl_xor(s[r], 8);
        }
        *(float4*)&xch[wid][l][0] = make_float4(s[0], s[1], s[2], s[3]);
        __syncthreads();                                   // b3: partial sums
        {
            float4 po = *(const float4*)&xch[wid ^ 1][l][0];
            float rt[4];
            rt[0] = __builtin_amdgcn_rcpf(s[0] + po.x);
            rt[1] = __builtin_amdgcn_rcpf(s[1] + po.y);
            rt[2] = __builtin_amdgcn_rcpf(s[2] + po.z);
            rt[3] = __builtin_amdgcn_rcpf(s[3] + po.w);
            float sm[4], ap[4];
            #pragma unroll
            for (int r = 0; r < 4; ++r) sm[r] = e[r] * rt[r];
            asacc += sm[0] + sm[1] + sm[2] + sm[3];
            ap[0] = sm[0] * sp4.x; ap[1] = sm[1] * sp4.y;
            ap[2] = sm[2] * sp4.z; ap[3] = sm[3] * sp4.w;
            ushort4 h, lo;
            split4t(ap[0], ap[1], ap[2], ap[3], h, lo);
            int ib = (nt * 16 + ln) * 40 + mt * 16 + 4 * q;
            *(ushort4*)&aph[ib] = h;
            *(ushort4*)&apl[ib] = lo;
        }
        __syncthreads();                                   // b4: a' ready

        // ================= GEMM2: aggT (d x k), contract p ====================
        bf16x8 A2h[2], A2l[2], B2h[2], B2l[2];
        #pragma unroll
        for (int m2 = 0; m2 < 2; ++m2) {
            int ia = ((2 * wid + m2) * 16 + ln) * 40 + 8 * q;
            A2h[m2] = *(const bf16x8*)&xDh[ia];
            A2l[m2] = *(const bf16x8*)&xDl[ia];
        }
        #pragma unroll
        for (int n2 = 0; n2 < 2; ++n2) {
            int ib = (n2 * 16 + ln) * 40 + 8 * q;
            B2h[n2] = *(const bf16x8*)&aph[ib];
            B2l[n2] = *(const bf16x8*)&apl[ib];
        }
        #pragma unroll
        for (int m2 = 0; m2 < 2; ++m2)
            #pragma unroll
            for (int n2 = 0; n2 < 2; ++n2) {
                acc2[m2][n2] = MFMA(A2h[m2], B2h[n2], acc2[m2][n2]);
                acc2[m2][n2] = MFMA(A2h[m2], B2l[n2], acc2[m2][n2]);
                acc2[m2][n2] = MFMA(A2l[m2], B2h[n2], acc2[m2][n2]);
            }
        __syncthreads();                                   // b5: end of tile
    }

    // ================= epilogue: partials to workspace =======================
    const int base = ((n * S_SPL + ps) * K_CL) * D_CH;
    #pragma unroll
    for (int m2 = 0; m2 < 2; ++m2)
        #pragma unroll
        for (int n2 = 0; n2 < 2; ++n2) {
            int k = n2 * 16 + ln;
            #pragma unroll
            for (int r = 0; r < 4; ++r) {
                int d = (2 * wid + m2) * 16 + 4 * q + r;
                aggp[base + k * D_CH + d] = acc2[m2][n2][r];
            }
        }
    asacc += __shfl_xor(asacc, 16);
    asacc += __shfl_xor(asacc, 32);
    if (l < 16) asw[wid][l] = asacc;
    __syncthreads();
    if (tid < K_CL)
        asump[(n * S_SPL + ps) * K_CL + tid] =
            asw[tid >> 4][tid & 15] + asw[(tid >> 4) + 2][tid & 15];
}

__global__ __launch_bounds__(256)
void netvlad_finish(const float* __restrict__ aggp, const float* __restrict__ asump,
                    const float* __restrict__ cen, float* __restrict__ out)
{
    __shared__ float red[K_CL][8];
    __shared__ float gw[4];
    __shared__ float gss;
    const int tid = threadIdx.x;
    const int n = blockIdx.x;
    const int k = tid >> 3;
    const int d0 = (tid & 7) << 4;

    float v[16];
    #pragma unroll
    for (int i = 0; i < 16; ++i) v[i] = 0.0f;
    float as = 0.0f;
    for (int qq = 0; qq < S_SPL; ++qq) {
        const float* src = aggp + (((n * S_SPL + qq) * K_CL) + k) * D_CH + d0;
        #pragma unroll
        for (int c = 0; c < 4; ++c) {
            float4 t4 = *(const float4*)(src + (c << 2));
            v[4*c+0] += t4.x; v[4*c+1] += t4.y; v[4*c+2] += t4.z; v[4*c+3] += t4.w;
        }
        as += asump[(n * S_SPL + qq) * K_CL + k];
    }
    const float* cp = cen + k * D_CH + d0;
    float ssq = 0.0f;
    #pragma unroll
    for (int c = 0; c < 4; ++c) {
        float4 c4 = *(const float4*)(cp + (c << 2));
        v[4*c+0] -= as * c4.x;
        v[4*c+1] -= as * c4.y;
        v[4*c+2] -= as * c4.z;
        v[4*c+3] -= as * c4.w;
    }
    #pragma unroll
    for (int i = 0; i < 16; ++i) ssq += v[i] * v[i];
    red[k][tid & 7] = ssq;
    __syncthreads();
    float s2 = 0.0f;
    #pragma unroll
    for (int j = 0; j < 8; ++j) s2 += red[k][j];
    const float sc1 = 1.0f / fmaxf(sqrtf(s2), 1e-12f);
    #pragma unroll
    for (int i = 0; i < 16; ++i) v[i] *= sc1;
    float g = ssq * sc1 * sc1;
    #pragma unroll
    for (int off = 1; off < 64; off <<= 1) g += __shfl_xor(g, off);
    if ((tid & 63) == 0) gw[tid >> 6] = g;
    __syncthreads();
    if (tid == 0) gss = 1.0f / fmaxf(sqrtf(gw[0] + gw[1] + gw[2] + gw[3]), 1e-12f);
    __syncthreads();
    const float gsc = gss;
    float* op = out + (size_t)n * (K_CL * D_CH) + k * D_CH + d0;
    #pragma unroll
    for (int c = 0; c < 4; ++c) {
        *(float4*)(op + (c << 2)) =
            make_float4(v[4*c+0]*gsc, v[4*c+1]*gsc, v[4*c+2]*gsc, v[4*c+3]*gsc);
    }
}

extern "C" void kernel_launch(void* const* d_in, const int* in_sizes, int n_in,
                              void* d_out, int out_size, void* d_ws, size_t ws_size,
                              hipStream_t stream)
{
    const float* x   = (const float*)d_in[0];
    const float* w   = (const float*)d_in[1];
    const float* cen = (const float*)d_in[2];
    float* out = (float*)d_out;

    float* aggp  = (float*)d_ws;                                    // [64][8][32][128] = 8 MB
    float* asump = aggp + (size_t)N_IMG * S_SPL * K_CL * D_CH;      // [64][8][32]

    netvlad_main<<<N_IMG * S_SPL, 256, 0, stream>>>(x, w, aggp, asump);
    netvlad_finish<<<N_IMG, 256, 0, stream>>>(aggp, asump, cen, out);
}

// Round 9
// 52.466 us; speedup vs baseline: 2.4048x; 1.0067x over previous
//
#include <hip/hip_runtime.h>
#include <math.h>

#define N_IMG 64
#define D_CH  128
#define P_PIX 4096
#define K_CL  32
#define S_SPL 8
#define P_BLK (P_PIX / S_SPL)   // 512 pixels per block
#define TP    32                // pixels per tile
#define N_TILE (P_BLK / TP)     // 16 tiles

typedef __attribute__((ext_vector_type(8))) short bf16x8;
typedef __attribute__((ext_vector_type(4))) float f32x4;

#define MFMA(a, b, c) __builtin_amdgcn_mfma_f32_16x16x32_bf16(a, b, c, 0, 0, 0)

// Barrier that does NOT drain vmcnt: LDS-release (lgkmcnt) + s_barrier.
// Keeps prefetch global loads in flight across the barrier (HK/m201 pattern).
#define BAR() do {                                            \
    asm volatile("s_waitcnt lgkmcnt(0)" ::: "memory");        \
    __builtin_amdgcn_s_barrier();                             \
} while (0)

// Dekker-style truncation split: f = hi + lo + O(2^-17 |f|), hi/lo bf16.
static __device__ __forceinline__ void split4t(float a, float b, float c, float d,
                                               ushort4 &h, ushort4 &l) {
    unsigned ua = __float_as_uint(a), ub = __float_as_uint(b);
    unsigned uc = __float_as_uint(c), ud = __float_as_uint(d);
    h.x = (ushort)(ua >> 16); h.y = (ushort)(ub >> 16);
    h.z = (ushort)(uc >> 16); h.w = (ushort)(ud >> 16);
    float ra = a - __uint_as_float(ua & 0xffff0000u);
    float rb = b - __uint_as_float(ub & 0xffff0000u);
    float rc = c - __uint_as_float(uc & 0xffff0000u);
    float rd = d - __uint_as_float(ud & 0xffff0000u);
    l.x = (ushort)(__float_as_uint(ra) >> 16);
    l.y = (ushort)(__float_as_uint(rb) >> 16);
    l.z = (ushort)(__float_as_uint(rc) >> 16);
    l.w = (ushort)(__float_as_uint(rd) >> 16);
}

// LDS element-index layouts (ushort):
//   xT (p-major):  row p (0..31), 136 elems/row (272 B, pad kills stride conflicts)
//   xD (d-major):  row d (0..127), 40 elems/row (80 B)
//   a'  (k-major): row k (0..31), 40 elems/row
__global__ __launch_bounds__(256)
void netvlad_main(const float* __restrict__ x, const float* __restrict__ w,
                  float* __restrict__ aggp, float* __restrict__ asump)
{
    __shared__ __align__(16) ushort xTh[32 * 136], xTl[32 * 136];
    __shared__ __align__(16) ushort xDh[128 * 40], xDl[128 * 40];
    __shared__ __align__(16) ushort aph[32 * 40],  apl[32 * 40];
    __shared__ __align__(16) float  xch[4][64][4];
    __shared__ float pbuf[4][32];   // per-wave ssq partials (pixel-indexed)
    __shared__ float asw[4][16];

    const int tid = threadIdx.x;
    const int n   = blockIdx.x >> 3;
    const int ps  = blockIdx.x & 7;

    const int l   = tid & 63;
    const int wid = tid >> 6;
    const int q   = l >> 4;       // 16-lane group
    const int ln  = l & 15;
    const int mt  = wid >> 1;     // GEMM1 pixel m-tile (0/1)
    const int nt  = wid & 1;      // GEMM1/2 k n-tile (0/1)

    // ---- preload conv_w fragments into registers (hi/lo bf16), per wave's nt ----
    bf16x8 wh[4], wl[4];
    #pragma unroll
    for (int kk = 0; kk < 4; ++kk) {
        const float* wp = w + (nt * 16 + ln) * D_CH + kk * 32 + 8 * q;
        float4 wa = *(const float4*)wp;
        float4 wb = *(const float4*)(wp + 4);
        ushort4 h1, l1, h2, l2;
        split4t(wa.x, wa.y, wa.z, wa.w, h1, l1);
        split4t(wb.x, wb.y, wb.z, wb.w, h2, l2);
        wh[kk][0] = (short)h1.x; wh[kk][1] = (short)h1.y; wh[kk][2] = (short)h1.z; wh[kk][3] = (short)h1.w;
        wh[kk][4] = (short)h2.x; wh[kk][5] = (short)h2.y; wh[kk][6] = (short)h2.z; wh[kk][7] = (short)h2.w;
        wl[kk][0] = (short)l1.x; wl[kk][1] = (short)l1.y; wl[kk][2] = (short)l1.z; wl[kk][3] = (short)l1.w;
        wl[kk][4] = (short)l2.x; wl[kk][5] = (short)l2.y; wl[kk][6] = (short)l2.z; wl[kk][7] = (short)l2.w;
    }

    f32x4 acc2[2][2];   // aggT accumulators: [m-subtile(d)][n-tile(k)]
    #pragma unroll
    for (int a = 0; a < 2; ++a)
        #pragma unroll
        for (int b = 0; b < 2; ++b)
            acc2[a][b] = (f32x4){0.f, 0.f, 0.f, 0.f};
    float asacc = 0.0f;

    const float* xin = x + (size_t)n * D_CH * P_PIX + ps * P_BLK;

    const int pT    = tid & 31;
    const int dbase = (tid >> 5) * 16;

    // ---- prologue: load tile 0 into registers ----
    float4 xv[4];
    float  tv[16];
    {
        const float* xt = xin;
        #pragma unroll
        for (int it = 0; it < 4; ++it) {
            int d = it * 32 + (tid >> 3);
            xv[it] = *(const float4*)(xt + d * P_PIX + 4 * (tid & 7));
        }
        #pragma unroll
        for (int j = 0; j < 16; ++j)
            tv[j] = xt[(size_t)(dbase + j) * P_PIX + pT];
    }

    for (int t = 0; t < N_TILE; ++t) {
        // ================= stage: regs -> LDS (both layouts) ==================
        #pragma unroll
        for (int it = 0; it < 4; ++it) {
            int d = it * 32 + (tid >> 3);
            ushort4 h, lo;
            split4t(xv[it].x, xv[it].y, xv[it].z, xv[it].w, h, lo);
            *(ushort4*)&xDh[d * 40 + 4 * (tid & 7)] = h;
            *(ushort4*)&xDl[d * 40 + 4 * (tid & 7)] = lo;
        }

        // xT staging + per-pixel ssq partial from tv registers
        float sq = 0.f;
        #pragma unroll
        for (int c = 0; c < 4; ++c) {
            ushort4 h, lo;
            split4t(tv[4*c+0], tv[4*c+1], tv[4*c+2], tv[4*c+3], h, lo);
            *(ushort4*)&xTh[pT * 136 + dbase + 4 * c] = h;
            *(ushort4*)&xTl[pT * 136 + dbase + 4 * c] = lo;
            sq += tv[4*c+0]*tv[4*c+0] + tv[4*c+1]*tv[4*c+1]
                + tv[4*c+2]*tv[4*c+2] + tv[4*c+3]*tv[4*c+3];
        }
        // reduce the wave's two d-chunks (lanes l and l^32 share pT)
        sq += __shfl_xor(sq, 32);
        if (l < 32) pbuf[wid][pT] = sq;

        // ---- prefetch tile t+1; loads stay in flight across the raw barriers ----
        if (t + 1 < N_TILE) {
            const float* xt2 = xin + (t + 1) * TP;
            #pragma unroll
            for (int it = 0; it < 4; ++it) {
                int d = it * 32 + (tid >> 3);
                xv[it] = *(const float4*)(xt2 + d * P_PIX + 4 * (tid & 7));
            }
            #pragma unroll
            for (int j = 0; j < 16; ++j)
                tv[j] = xt2[(size_t)(dbase + j) * P_PIX + pT];
        }
        BAR();                                             // b1: tiles staged

        // ---- per-wave 1/||x||: all waves, in-register (no barrier needed) ----
        float spx, spy, spz, spw;
        {
            int pp = l & 31;
            int jb = (l >> 5) * 2;
            float vsq = pbuf[jb][pp] + pbuf[jb + 1][pp];
            vsq += __shfl_xor(vsq, 32);
            float sSl = 1.0f / fmaxf(sqrtf(vsq), 1e-12f);  // lane holds sS[p=l&31]
            int p0 = mt * 16 + 4 * q;
            spx = __shfl(sSl, p0 + 0);
            spy = __shfl(sSl, p0 + 1);
            spz = __shfl(sSl, p0 + 2);
            spw = __shfl(sSl, p0 + 3);
        }

        // ================= GEMM1: logits (p x k), contract d ==================
        f32x4 acc1 = (f32x4){0.f, 0.f, 0.f, 0.f};
        #pragma unroll
        for (int kk = 0; kk < 4; ++kk) {
            int ia = (mt * 16 + ln) * 136 + kk * 32 + 8 * q;
            bf16x8 Ah = *(const bf16x8*)&xTh[ia];
            bf16x8 Al = *(const bf16x8*)&xTl[ia];
            acc1 = MFMA(Ah, wh[kk], acc1);
            acc1 = MFMA(Ah, wl[kk], acc1);
            acc1 = MFMA(Al, wh[kk], acc1);
        }

        // ================= softmax over k (in-register, no max-sub) ===========
        // lane holds logits for pixels p = mt*16+4q+r, k = nt*16+ln
        float e[4], s[4];
        e[0] = __builtin_expf(acc1[0] * spx);
        e[1] = __builtin_expf(acc1[1] * spy);
        e[2] = __builtin_expf(acc1[2] * spz);
        e[3] = __builtin_expf(acc1[3] * spw);
        #pragma unroll
        for (int r = 0; r < 4; ++r) {
            s[r] = e[r];
            s[r] += __shfl_xor(s[r], 1);
            s[r] += __shfl_xor(s[r], 2);
            s[r] += __shfl_xor(s[r], 4);
            s[r] += __shfl_xor(s[r], 8);
        }
        *(float4*)&xch[wid][l][0] = make_float4(s[0], s[1], s[2], s[3]);
        BAR();                                             // b3: partial sums
        {
            float4 po = *(const float4*)&xch[wid ^ 1][l][0];
            float rt[4];
            rt[0] = __builtin_amdgcn_rcpf(s[0] + po.x);
            rt[1] = __builtin_amdgcn_rcpf(s[1] + po.y);
            rt[2] = __builtin_amdgcn_rcpf(s[2] + po.z);
            rt[3] = __builtin_amdgcn_rcpf(s[3] + po.w);
            float sm[4], ap[4];
            #pragma unroll
            for (int r = 0; r < 4; ++r) sm[r] = e[r] * rt[r];
            asacc += sm[0] + sm[1] + sm[2] + sm[3];
            ap[0] = sm[0] * spx; ap[1] = sm[1] * spy;
            ap[2] = sm[2] * spz; ap[3] = sm[3] * spw;
            ushort4 h, lo;
            split4t(ap[0], ap[1], ap[2], ap[3], h, lo);
            int ib = (nt * 16 + ln) * 40 + mt * 16 + 4 * q;
            *(ushort4*)&aph[ib] = h;
            *(ushort4*)&apl[ib] = lo;
        }
        BAR();                                             // b4: a' ready

        // ================= GEMM2: aggT (d x k), contract p ====================
        bf16x8 A2h[2], A2l[2], B2h[2], B2l[2];
        #pragma unroll
        for (int m2 = 0; m2 < 2; ++m2) {
            int ia = ((2 * wid + m2) * 16 + ln) * 40 + 8 * q;
            A2h[m2] = *(const bf16x8*)&xDh[ia];
            A2l[m2] = *(const bf16x8*)&xDl[ia];
        }
        #pragma unroll
        for (int n2 = 0; n2 < 2; ++n2) {
            int ib = (n2 * 16 + ln) * 40 + 8 * q;
            B2h[n2] = *(const bf16x8*)&aph[ib];
            B2l[n2] = *(const bf16x8*)&apl[ib];
        }
        #pragma unroll
        for (int m2 = 0; m2 < 2; ++m2)
            #pragma unroll
            for (int n2 = 0; n2 < 2; ++n2) {
                acc2[m2][n2] = MFMA(A2h[m2], B2h[n2], acc2[m2][n2]);
                acc2[m2][n2] = MFMA(A2h[m2], B2l[n2], acc2[m2][n2]);
                acc2[m2][n2] = MFMA(A2l[m2], B2h[n2], acc2[m2][n2]);
            }
        BAR();                                             // b5: end of tile
    }

    // ================= epilogue: partials to workspace =======================
    const int base = ((n * S_SPL + ps) * K_CL) * D_CH;
    #pragma unroll
    for (int m2 = 0; m2 < 2; ++m2)
        #pragma unroll
        for (int n2 = 0; n2 < 2; ++n2) {
            int k = n2 * 16 + ln;
            #pragma unroll
            for (int r = 0; r < 4; ++r) {
                int d = (2 * wid + m2) * 16 + 4 * q + r;
                aggp[base + k * D_CH + d] = acc2[m2][n2][r];
            }
        }
    asacc += __shfl_xor(asacc, 16);
    asacc += __shfl_xor(asacc, 32);
    if (l < 16) asw[wid][l] = asacc;
    __syncthreads();
    if (tid < K_CL)
        asump[(n * S_SPL + ps) * K_CL + tid] =
            asw[tid >> 4][tid & 15] + asw[(tid >> 4) + 2][tid & 15];
}

__global__ __launch_bounds__(256)
void netvlad_finish(const float* __restrict__ aggp, const float* __restrict__ asump,
                    const float* __restrict__ cen, float* __restrict__ out)
{
    __shared__ float red[K_CL][8];
    __shared__ float gw[4];
    __shared__ float gss;
    const int tid = threadIdx.x;
    const int n = blockIdx.x;
    const int k = tid >> 3;
    const int d0 = (tid & 7) << 4;

    float v[16];
    #pragma unroll
    for (int i = 0; i < 16; ++i) v[i] = 0.0f;
    float as = 0.0f;
    for (int qq = 0; qq < S_SPL; ++qq) {
        const float* src = aggp + (((n * S_SPL + qq) * K_CL) + k) * D_CH + d0;
        #pragma unroll
        for (int c = 0; c < 4; ++c) {
            float4 t4 = *(const float4*)(src + (c << 2));
            v[4*c+0] += t4.x; v[4*c+1] += t4.y; v[4*c+2] += t4.z; v[4*c+3] += t4.w;
        }
        as += asump[(n * S_SPL + qq) * K_CL + k];
    }
    const float* cp = cen + k * D_CH + d0;
    float ssq = 0.0f;
    #pragma unroll
    for (int c = 0; c < 4; ++c) {
        float4 c4 = *(const float4*)(cp + (c << 2));
        v[4*c+0] -= as * c4.x;
        v[4*c+1] -= as * c4.y;
        v[4*c+2] -= as * c4.z;
        v[4*c+3] -= as * c4.w;
    }
    #pragma unroll
    for (int i = 0; i < 16; ++i) ssq += v[i] * v[i];
    red[k][tid & 7] = ssq;
    __syncthreads();
    float s2 = 0.0f;
    #pragma unroll
    for (int j = 0; j < 8; ++j) s2 += red[k][j];
    const float sc1 = 1.0f / fmaxf(sqrtf(s2), 1e-12f);
    #pragma unroll
    for (int i = 0; i < 16; ++i) v[i] *= sc1;
    float g = ssq * sc1 * sc1;
    #pragma unroll
    for (int off = 1; off < 64; off <<= 1) g += __shfl_xor(g, off);
    if ((tid & 63) == 0) gw[tid >> 6] = g;
    __syncthreads();
    if (tid == 0) gss = 1.0f / fmaxf(sqrtf(gw[0] + gw[1] + gw[2] + gw[3]), 1e-12f);
    __syncthreads();
    const float gsc = gss;
    float* op = out + (size_t)n * (K_CL * D_CH) + k * D_CH + d0;
    #pragma unroll
    for (int c = 0; c < 4; ++c) {
        *(float4*)(op + (c << 2)) =
            make_float4(v[4*c+0]*gsc, v[4*c+1]*gsc, v[4*c+2]*gsc, v[4*c+3]*gsc);
    }
}

extern "C" void kernel_launch(void* const* d_in, const int* in_sizes, int n_in,
                              void* d_out, int out_size, void* d_ws, size_t ws_size,
                              hipStream_t stream)
{
    const float* x   = (const float*)d_in[0];
    const float* w   = (const float*)d_in[1];
    const float* cen = (const float*)d_in[2];
    float* out = (float*)d_out;

    float* aggp  = (float*)d_ws;                                    // [64][8][32][128] = 8 MB
    float* asump = aggp + (size_t)N_IMG * S_SPL * K_CL * D_CH;      // [64][8][32]

    netvlad_main<<<N_IMG * S_SPL, 256, 0, stream>>>(x, w, aggp, asump);
    netvlad_finish<<<N_IMG, 256, 0, stream>>>(aggp, asump, cen, out);
}